// Round 14
// baseline (85.794 us; speedup 1.0000x reference)
//
#include <hip/hip_runtime.h>
#include <hip/hip_bf16.h>
#include <hip/hip_fp16.h>
#include <math.h>

// R26: isolated denominator change on the R25 base (best, 84.30us).
// R24 counters: attn 78% issue-saturated (VALU 13.4k + MFMA 6.7k of 25.8k
// cyc/SIMD) -> must remove issued work. Drop the ones-MFMA (1/3 of MFMA
// issues, 16 acc VGPRs); row-sums via fdot2 on af fragments. This exact
// denominator path (fdot2 + scomb tree + shfl-16/32 reduce + __shfl
// redistribution) PASSED in R18 (absmax bit-identical) — isolated now.
// Gemm = R23/R25 byte-identical. Predict dur 84.3 -> ~83.3-84.0; if flat,
// declare practical floor next round.

// Problem constants
#define F_IN  256
#define NOUT  256          // N_HEADS * N_HIDDEN
#define NB    8            // batch
#define NN    1024         // nodes
#define NH    8            // heads
#define ND    32           // hidden per head
#define NROWS (NB * NN)    // 8192
#define LOG2E 1.44269504f

typedef __attribute__((ext_vector_type(8))) short bf16x8;       // 8 bf16
typedef __attribute__((ext_vector_type(8))) _Float16 f16x8;     // 8 f16
typedef __attribute__((ext_vector_type(2))) _Float16 f16x2;     // packed f16
typedef __attribute__((ext_vector_type(4))) float f32x4;        // MFMA C/D

__device__ inline unsigned pk_f16(float a, float b) {
    union { __half2 h2; unsigned u; } c;
    c.h2 = __float22half2_rn(make_float2(a, b));
    return c.u;
}

// guaranteed packed-f16 ops (bit patterns in unsigned)
__device__ __forceinline__ unsigned pkmul(unsigned a, unsigned b) {
    unsigned r;
    asm("v_pk_mul_f16 %0, %1, %2" : "=v"(r) : "v"(a), "v"(b));
    return r;
}
__device__ __forceinline__ unsigned pkmax(unsigned a, unsigned b) {
    unsigned r;
    asm("v_pk_max_f16 %0, %1, %2" : "=v"(r) : "v"(a), "v"(b));
    return r;
}

#if __has_builtin(__builtin_amdgcn_fdot2)
__device__ __forceinline__ float dot2acc(unsigned af2, float c) {
    union { unsigned w; f16x2 v; } a; a.w = af2;
    const f16x2 one2 = (f16x2){(_Float16)1.0f, (_Float16)1.0f};
    return __builtin_amdgcn_fdot2(a.v, one2, c, false);
}
#else
__device__ __forceinline__ float dot2acc(unsigned af2, float c) {
    union { unsigned w; f16x2 v; } a; a.w = af2;
    return c + (float)a.v.x + (float)a.v.y;
}
#endif

// ---------------------------------------------------------------------------
// Kernel 1: g = vertex @ w_vert via single-pass f16 MFMA, split-k 2-way.
// Byte-identical to R23/R25.
// ---------------------------------------------------------------------------
__global__ __launch_bounds__(256, 4) void gat_gemm_kernel(
    const float* __restrict__ vertex, const float* __restrict__ w_vert,
    const float* __restrict__ attn_w, unsigned short* __restrict__ gT,
    float* __restrict__ ssT, float* __restrict__ sdT)
{
    // staging: [bk(16 blocks: ktile*2+nt)][lane(64)][8 f16] = 16 KB
    __shared__ __align__(16) unsigned short bHi[8192];
    f32x4 (*comb)[4][64] = reinterpret_cast<f32x4(*)[4][64]>(bHi);
    unsigned short (*trans)[72] =
        reinterpret_cast<unsigned short(*)[72]>(bHi + 4096);

    const int t = threadIdx.x, lane = t & 63, wv = t >> 6;
    const int mt = wv & 1, kh = wv >> 1;
    const int il = lane & 15, ql = lane >> 4;
    const int h = blockIdx.y, gr0 = blockIdx.x * 64;
    const int b = gr0 >> 10, bh = b * NH + h;

    {
        const int n  = t & 31;
        const int kb = t >> 5;               // 0..7
        const int il_s = n & 15, nt_s = n >> 4;
        #pragma unroll
        for (int q = 0; q < 4; ++q) {
            const int k0 = kb * 8 + 64 * q;  // 8-aligned, covers 0..255
            const float* wp = w_vert + (size_t)k0 * NOUT + h * 32 + n;
            float f[8];
            #pragma unroll
            for (int j = 0; j < 8; ++j) f[j] = wp[j * NOUT];
            unsigned hu[4];
            #pragma unroll
            for (int j2 = 0; j2 < 4; ++j2)
                hu[j2] = pk_f16(f[2 * j2], f[2 * j2 + 1]);
            const int ktile = k0 >> 5;           // 0..7
            const int qlb   = (k0 & 31) >> 3;    // 0..3
            const int off   = (ktile * 2 + nt_s) * 512 + (qlb * 16 + il_s) * 8;
            *(uint4*)&bHi[off] = *(const uint4*)hu;
        }
    }
    __syncthreads();

    const float* arow0 = vertex + (size_t)(gr0 + mt * 32 + il) * F_IN + kh * 128 + ql * 8;
    const float* arow1 = arow0 + 16 * F_IN;

    f32x4 c00 = {0.f, 0.f, 0.f, 0.f}, c01 = c00, c10 = c00, c11 = c00;

    #pragma unroll
    for (int kk = 0; kk < 4; ++kk) {
        float4 a0a = *(const float4*)(arow0 + kk * 32);
        float4 a0b = *(const float4*)(arow0 + kk * 32 + 4);
        float4 a1a = *(const float4*)(arow1 + kk * 32);
        float4 a1b = *(const float4*)(arow1 + kk * 32 + 4);

        const int bkb = (kh * 4 + kk) * 2;
        f16x8 bh0 = *(const f16x8*)&bHi[bkb * 512 + lane * 8];
        f16x8 bh1 = *(const f16x8*)&bHi[(bkb + 1) * 512 + lane * 8];

        union { f16x8 v; unsigned u[4]; } A0, A1;
        A0.u[0] = pk_f16(a0a.x, a0a.y); A0.u[1] = pk_f16(a0a.z, a0a.w);
        A0.u[2] = pk_f16(a0b.x, a0b.y); A0.u[3] = pk_f16(a0b.z, a0b.w);
        A1.u[0] = pk_f16(a1a.x, a1a.y); A1.u[1] = pk_f16(a1a.z, a1a.w);
        A1.u[2] = pk_f16(a1b.x, a1b.y); A1.u[3] = pk_f16(a1b.z, a1b.w);

        c00 = __builtin_amdgcn_mfma_f32_16x16x32_f16(A0.v, bh0, c00, 0, 0, 0);
        c01 = __builtin_amdgcn_mfma_f32_16x16x32_f16(A0.v, bh1, c01, 0, 0, 0);
        c10 = __builtin_amdgcn_mfma_f32_16x16x32_f16(A1.v, bh0, c10, 0, 0, 0);
        c11 = __builtin_amdgcn_mfma_f32_16x16x32_f16(A1.v, bh1, c11, 0, 0, 0);
    }

    // staging LDS dead from here; alias as combine + transpose buffers
    __syncthreads();
    if (kh == 1) {
        comb[mt][0][lane] = c00; comb[mt][1][lane] = c01;
        comb[mt][2][lane] = c10; comb[mt][3][lane] = c11;
    }
    __syncthreads();
    if (kh == 0) {
        c00 = c00 + comb[mt][0][lane]; c01 = c01 + comb[mt][1][lane];
        c10 = c10 + comb[mt][2][lane]; c11 = c11 + comb[mt][3][lane];

        const float wsv0 = attn_w[il],      wsv1 = attn_w[16 + il];
        const float wdv0 = attn_w[ND + il], wdv1 = attn_w[ND + 16 + il];
        const int j0 = (gr0 & 1023) + mt * 32;

        #pragma unroll
        for (int g = 0; g < 2; ++g) {
            f32x4 cA = g ? c10 : c00;   // d = il
            f32x4 cB = g ? c11 : c01;   // d = 16+il
            const int jl = mt * 32 + g * 16 + ql * 4;   // local j in [0,64)

            // transpose into padded LDS — g stored as f16
            *(unsigned*)&trans[il][jl]          = pk_f16(cA[0], cA[1]);
            *(unsigned*)&trans[il][jl + 2]      = pk_f16(cA[2], cA[3]);
            *(unsigned*)&trans[16 + il][jl]     = pk_f16(cB[0], cB[1]);
            *(unsigned*)&trans[16 + il][jl + 2] = pk_f16(cB[2], cB[3]);

            const int jr = j0 + g * 16 + ql * 4;
            #pragma unroll
            for (int reg = 0; reg < 4; ++reg) {
                float ps = cA[reg] * wsv0 + cB[reg] * wsv1;
                float pd = cA[reg] * wdv0 + cB[reg] * wdv1;
                #pragma unroll
                for (int off = 1; off < 16; off <<= 1) {
                    ps += __shfl_xor(ps, off);
                    pd += __shfl_xor(pd, off);
                }
                if (il == 0) {
                    ssT[bh * NN + jr + reg] = ps;
                    sdT[bh * NN + jr + reg] = pd;
                }
            }
        }
    }
    __syncthreads();

    // coalesced gT store: thread t -> d = t>>3, 8 consecutive j (16 B)
    {
        const int d  = t >> 3;
        const int jo = (t & 7) * 8;
        uint4 v = *(const uint4*)&trans[d][jo];
        *(uint4*)(gT + ((size_t)(bh * ND) + d) * NN + (gr0 & 1023) + jo) = v;
    }
}

// ---------------------------------------------------------------------------
// Kernel 2 (exp-free MFMA attn, pk-asm af path, fdot2 denominator):
//   R25 structure; cs ones-MFMA removed — row-sums S[mt] accumulated via
//   v_dot2_f32_f16 on af (A-frag row = lane&15), quarter-combined through
//   scomb, reduced over ql via shfl_xor(16,32), redistributed via __shfl.
// ---------------------------------------------------------------------------
__global__ __launch_bounds__(256, 4) void gat_attn_kernel(
    const unsigned short* __restrict__ gT, const float* __restrict__ ssT,
    const float* __restrict__ sdT, float* __restrict__ out)
{
    __shared__ __align__(16) unsigned short BpH[NN];   // 2 KB, f16 bits
    __shared__ __align__(16) unsigned short BnH[NN];   // 2 KB, f16 bits
    __shared__ f32x4 ccomb[2][8][64];                  // 16 KB
    __shared__ float scomb[2][4][64];                  // 2 KB
    __shared__ float red[4];

    const int bid = blockIdx.x;
    const int bh = bid & 63;                 // b*NH + h  (bid%8 = h)
    const int b = bh >> 3, h = bh & 7;
    const int i0 = (bid >> 6) * 64;
    const int t = threadIdx.x, lane = t & 63, jq = t >> 6;
    const int il = lane & 15, ql = lane >> 4;

    // ---- phase 0: BpH/BnH (f16) + global sd max + per-lane i-constants ----
    float sdv[4]; float M = -3.0e38f;
    #pragma unroll
    for (int q = 0; q < 4; ++q) {
        sdv[q] = sdT[bh * NN + t + 256 * q];
        M = fmaxf(M, sdv[q]);
    }
    #pragma unroll
    for (int off = 32; off >= 1; off >>= 1)
        M = fmaxf(M, __shfl_xor(M, off));
    if (lane == 0) red[jq] = M;
    #pragma unroll
    for (int q = 0; q < 4; ++q) {
        union { _Float16 h; unsigned short u; } cp, cn;
        cp.h = (_Float16)exp2f(sdv[q] * LOG2E);
        cn.h = (_Float16)exp2f(0.2f * LOG2E * sdv[q]);
        BpH[t + 256 * q] = cp.u;
        BnH[t + 256 * q] = cn.u;
    }
    __syncthreads();
    M = fmaxf(fmaxf(red[0], red[1]), fmaxf(red[2], red[3]));

    unsigned apw[4], anw[4];   // f16x2 splats as bit patterns
    #pragma unroll
    for (int mt = 0; mt < 4; ++mt) {
        const float si = ssT[bh * NN + i0 + mt * 16 + il];
        float x = si + M; x = fmaxf(x, 0.2f * x);
        const float mk = x * LOG2E;
        const float ah = exp2f(fmaf(si, LOG2E, -mk));
        const float nh = exp2f(fmaf(0.2f * si, LOG2E, -mk));
        apw[mt] = pk_f16(ah, ah);
        anw[mt] = pk_f16(nh, nh);
    }

    const unsigned short* gb0 = gT + ((size_t)(bh * ND) + il) * NN + jq * 256 + ql * 8;
    const unsigned short* gb1 = gb0 + 16 * NN;
    const unsigned short* bpq = BpH + jq * 256 + ql * 8;
    const unsigned short* bnq = BnH + jq * 256 + ql * 8;

    f32x4 c0[4], c1[4];
    float S[4] = {0.f, 0.f, 0.f, 0.f};
    #pragma unroll
    for (int mt = 0; mt < 4; ++mt) {
        c0[mt] = (f32x4){0.f, 0.f, 0.f, 0.f};
        c1[mt] = c0[mt];
    }

    // ---- main loop: wave jq handles j in [jq*256, jq*256+256) ----
    // Software pipeline: gT (global) prefetch depth 4, Bp/Bn (LDS) depth 2.
    f16x8 b0b[4], b1b[4];
    union { uint4 q; unsigned w[4]; } pwb[2], nwb[2];
    #pragma unroll
    for (int s = 0; s < 4; ++s) {
        b0b[s] = *(const f16x8*)(gb0 + s * 32);
        b1b[s] = *(const f16x8*)(gb1 + s * 32);
    }
    #pragma unroll
    for (int s = 0; s < 2; ++s) {
        pwb[s].q = *(const uint4*)(bpq + s * 32);
        nwb[s].q = *(const uint4*)(bnq + s * 32);
    }

    #pragma unroll
    for (int s = 0; s < 8; ++s) {
        const int gbi = s & 3, lbi = s & 1;
        const f16x8 bf0 = b0b[gbi];
        const f16x8 bf1 = b1b[gbi];
        unsigned pw0 = pwb[lbi].w[0], pw1 = pwb[lbi].w[1];
        unsigned pw2 = pwb[lbi].w[2], pw3 = pwb[lbi].w[3];
        unsigned nw0 = nwb[lbi].w[0], nw1 = nwb[lbi].w[1];
        unsigned nw2 = nwb[lbi].w[2], nw3 = nwb[lbi].w[3];

        if (s < 4) {   // prefetch gT for s+4
            b0b[gbi] = *(const f16x8*)(gb0 + (s + 4) * 32);
            b1b[gbi] = *(const f16x8*)(gb1 + (s + 4) * 32);
        }
        if (s < 6) {   // prefetch Bp/Bn for s+2
            pwb[lbi].q = *(const uint4*)(bpq + (s + 2) * 32);
            nwb[lbi].q = *(const uint4*)(bnq + (s + 2) * 32);
        }

        const unsigned pww[4] = {pw0, pw1, pw2, pw3};
        const unsigned nww[4] = {nw0, nw1, nw2, nw3};
        #pragma unroll
        for (int mt = 0; mt < 4; ++mt) {
            union { f16x8 v; unsigned u[4]; } af;
            float sacc = S[mt];
            #pragma unroll
            for (int u = 0; u < 4; ++u) {
                af.u[u] = pkmax(pkmul(pww[u], apw[mt]),
                                pkmul(nww[u], anw[mt]));
                sacc = dot2acc(af.u[u], sacc);
            }
            S[mt] = sacc;
            c0[mt] = __builtin_amdgcn_mfma_f32_16x16x32_f16(af.v, bf0, c0[mt], 0, 0, 0);
            c1[mt] = __builtin_amdgcn_mfma_f32_16x16x32_f16(af.v, bf1, c1[mt], 0, 0, 0);
        }
    }

    // ---- quarter-combine tree: 2,3 -> 0,1; then 1 -> 0 ----
    if (jq >= 2) {
        #pragma unroll
        for (int mt = 0; mt < 4; ++mt) {
            ccomb[jq - 2][mt * 2 + 0][lane] = c0[mt];
            ccomb[jq - 2][mt * 2 + 1][lane] = c1[mt];
            scomb[jq - 2][mt][lane] = S[mt];
        }
    }
    __syncthreads();
    if (jq < 2) {
        #pragma unroll
        for (int mt = 0; mt < 4; ++mt) {
            c0[mt] = c0[mt] + ccomb[jq][mt * 2 + 0][lane];
            c1[mt] = c1[mt] + ccomb[jq][mt * 2 + 1][lane];
            S[mt] += scomb[jq][mt][lane];
        }
    }
    __syncthreads();
    if (jq == 1) {
        #pragma unroll
        for (int mt = 0; mt < 4; ++mt) {
            ccomb[0][mt * 2 + 0][lane] = c0[mt];
            ccomb[0][mt * 2 + 1][lane] = c1[mt];
            scomb[0][mt][lane] = S[mt];
        }
    }
    __syncthreads();
    if (jq == 0) {
        #pragma unroll
        for (int mt = 0; mt < 4; ++mt) {
            c0[mt] = c0[mt] + ccomb[0][mt * 2 + 0][lane];
            c1[mt] = c1[mt] + ccomb[0][mt * 2 + 1][lane];
            S[mt] += scomb[0][mt][lane];
            // S[mt]: partial row-sum for row il over this lane's j-slots;
            // reduce over ql (lanes il+16*ql hold disjoint j's)
            S[mt] += __shfl_xor(S[mt], 16);
            S[mt] += __shfl_xor(S[mt], 32);

            // C/D: col=il (d), row=ql*4+reg (i); divisor = S of row ql*4+reg,
            // held (replicated over ql') by lanes with il' = ql*4+reg.
            float* ob = out + (size_t)(b * NN + i0 + mt * 16 + ql * 4) * NOUT + h * ND + il;
            #pragma unroll
            for (int reg = 0; reg < 4; ++reg) {
                const int rr = ql * 4 + reg;               // row within tile
                const float Srow = __shfl(S[mt], (ql << 4) | rr);
                const float r = 1.0f / Srow;
                ob[reg * NOUT]      = c0[mt][reg] * r;
                ob[reg * NOUT + 16] = c1[mt][reg] * r;
            }
        }
    }
}

// ---------------------------------------------------------------------------
extern "C" void kernel_launch(void* const* d_in, const int* in_sizes, int n_in,
                              void* d_out, int out_size, void* d_ws, size_t ws_size,
                              hipStream_t stream) {
    (void)in_sizes; (void)n_in; (void)out_size; (void)ws_size;
    const float* vertex = (const float*)d_in[0];
    const float* w_vert = (const float*)d_in[1];
    const float* attn_w = (const float*)d_in[2];
    float* out = (float*)d_out;

    char* ws = (char*)d_ws;
    unsigned short* gT = (unsigned short*)ws;                          // 4 MB
    float* ssT = (float*)(ws + ((size_t)NB * NH * ND * NN * 2));
    float* sdT = ssT + (size_t)NB * NH * NN;

    gat_gemm_kernel<<<dim3(128, NH), 256, 0, stream>>>(vertex, w_vert, attn_w,
                                                       gT, ssT, sdT);
    gat_attn_kernel<<<1024, 256, 0, stream>>>(gT, ssT, sdT, out);
}

// Round 15
// 84.891 us; speedup vs baseline: 1.0106x; 1.0106x over previous
//
#include <hip/hip_runtime.h>
#include <hip/hip_bf16.h>
#include <hip/hip_fp16.h>
#include <math.h>

// R27: REVERT to R25 (best, 84.30us). R26's fdot2 denominator regressed
// (+1.5us): fdot2 is VALU, attn is VALU-bound (13.4k VALU vs 6.7k MFMA of
// 25.8k cyc/SIMD) — moving the denominator from the underutilized MFMA pipe
// to the bottleneck VALU pipe (with a serial sacc chain + epilogue shfl) was
// a pipe-rebalancing error. The ones-MFMA denominator is correctly placed.
// This build = R23 gemm (single-pass f16 MFMA) + R25 attn (pk-asm af-gen,
// pipelined loads, ones-MFMA denominator). Expect dur ~84.3 +- 0.5; if it
// reproduces, declare practical roofline next round:
//   metric = fills ~46us (HBM-roofline harness poison) + ~7 graph gaps
//   ~20us + issue-saturated kernels ~17us; no kernel lever left > 1us.

// Problem constants
#define F_IN  256
#define NOUT  256          // N_HEADS * N_HIDDEN
#define NB    8            // batch
#define NN    1024         // nodes
#define NH    8            // heads
#define ND    32           // hidden per head
#define NROWS (NB * NN)    // 8192
#define LOG2E 1.44269504f

typedef __attribute__((ext_vector_type(8))) short bf16x8;       // 8 bf16
typedef __attribute__((ext_vector_type(8))) _Float16 f16x8;     // 8 f16
typedef __attribute__((ext_vector_type(2))) _Float16 f16x2;     // packed f16
typedef __attribute__((ext_vector_type(4))) float f32x4;        // MFMA C/D

__device__ inline unsigned pk_f16(float a, float b) {
    union { __half2 h2; unsigned u; } c;
    c.h2 = __float22half2_rn(make_float2(a, b));
    return c.u;
}

// guaranteed packed-f16 ops (bit patterns in unsigned)
__device__ __forceinline__ unsigned pkmul(unsigned a, unsigned b) {
    unsigned r;
    asm("v_pk_mul_f16 %0, %1, %2" : "=v"(r) : "v"(a), "v"(b));
    return r;
}
__device__ __forceinline__ unsigned pkmax(unsigned a, unsigned b) {
    unsigned r;
    asm("v_pk_max_f16 %0, %1, %2" : "=v"(r) : "v"(a), "v"(b));
    return r;
}

// ---------------------------------------------------------------------------
// Kernel 1: g = vertex @ w_vert via single-pass f16 MFMA, split-k 2-way.
// Byte-identical to R23/R25.
// ---------------------------------------------------------------------------
__global__ __launch_bounds__(256, 4) void gat_gemm_kernel(
    const float* __restrict__ vertex, const float* __restrict__ w_vert,
    const float* __restrict__ attn_w, unsigned short* __restrict__ gT,
    float* __restrict__ ssT, float* __restrict__ sdT)
{
    // staging: [bk(16 blocks: ktile*2+nt)][lane(64)][8 f16] = 16 KB
    __shared__ __align__(16) unsigned short bHi[8192];
    f32x4 (*comb)[4][64] = reinterpret_cast<f32x4(*)[4][64]>(bHi);
    unsigned short (*trans)[72] =
        reinterpret_cast<unsigned short(*)[72]>(bHi + 4096);

    const int t = threadIdx.x, lane = t & 63, wv = t >> 6;
    const int mt = wv & 1, kh = wv >> 1;
    const int il = lane & 15, ql = lane >> 4;
    const int h = blockIdx.y, gr0 = blockIdx.x * 64;
    const int b = gr0 >> 10, bh = b * NH + h;

    {
        const int n  = t & 31;
        const int kb = t >> 5;               // 0..7
        const int il_s = n & 15, nt_s = n >> 4;
        #pragma unroll
        for (int q = 0; q < 4; ++q) {
            const int k0 = kb * 8 + 64 * q;  // 8-aligned, covers 0..255
            const float* wp = w_vert + (size_t)k0 * NOUT + h * 32 + n;
            float f[8];
            #pragma unroll
            for (int j = 0; j < 8; ++j) f[j] = wp[j * NOUT];
            unsigned hu[4];
            #pragma unroll
            for (int j2 = 0; j2 < 4; ++j2)
                hu[j2] = pk_f16(f[2 * j2], f[2 * j2 + 1]);
            const int ktile = k0 >> 5;           // 0..7
            const int qlb   = (k0 & 31) >> 3;    // 0..3
            const int off   = (ktile * 2 + nt_s) * 512 + (qlb * 16 + il_s) * 8;
            *(uint4*)&bHi[off] = *(const uint4*)hu;
        }
    }
    __syncthreads();

    const float* arow0 = vertex + (size_t)(gr0 + mt * 32 + il) * F_IN + kh * 128 + ql * 8;
    const float* arow1 = arow0 + 16 * F_IN;

    f32x4 c00 = {0.f, 0.f, 0.f, 0.f}, c01 = c00, c10 = c00, c11 = c00;

    #pragma unroll
    for (int kk = 0; kk < 4; ++kk) {
        float4 a0a = *(const float4*)(arow0 + kk * 32);
        float4 a0b = *(const float4*)(arow0 + kk * 32 + 4);
        float4 a1a = *(const float4*)(arow1 + kk * 32);
        float4 a1b = *(const float4*)(arow1 + kk * 32 + 4);

        const int bkb = (kh * 4 + kk) * 2;
        f16x8 bh0 = *(const f16x8*)&bHi[bkb * 512 + lane * 8];
        f16x8 bh1 = *(const f16x8*)&bHi[(bkb + 1) * 512 + lane * 8];

        union { f16x8 v; unsigned u[4]; } A0, A1;
        A0.u[0] = pk_f16(a0a.x, a0a.y); A0.u[1] = pk_f16(a0a.z, a0a.w);
        A0.u[2] = pk_f16(a0b.x, a0b.y); A0.u[3] = pk_f16(a0b.z, a0b.w);
        A1.u[0] = pk_f16(a1a.x, a1a.y); A1.u[1] = pk_f16(a1a.z, a1a.w);
        A1.u[2] = pk_f16(a1b.x, a1b.y); A1.u[3] = pk_f16(a1b.z, a1b.w);

        c00 = __builtin_amdgcn_mfma_f32_16x16x32_f16(A0.v, bh0, c00, 0, 0, 0);
        c01 = __builtin_amdgcn_mfma_f32_16x16x32_f16(A0.v, bh1, c01, 0, 0, 0);
        c10 = __builtin_amdgcn_mfma_f32_16x16x32_f16(A1.v, bh0, c10, 0, 0, 0);
        c11 = __builtin_amdgcn_mfma_f32_16x16x32_f16(A1.v, bh1, c11, 0, 0, 0);
    }

    // staging LDS dead from here; alias as combine + transpose buffers
    __syncthreads();
    if (kh == 1) {
        comb[mt][0][lane] = c00; comb[mt][1][lane] = c01;
        comb[mt][2][lane] = c10; comb[mt][3][lane] = c11;
    }
    __syncthreads();
    if (kh == 0) {
        c00 = c00 + comb[mt][0][lane]; c01 = c01 + comb[mt][1][lane];
        c10 = c10 + comb[mt][2][lane]; c11 = c11 + comb[mt][3][lane];

        const float wsv0 = attn_w[il],      wsv1 = attn_w[16 + il];
        const float wdv0 = attn_w[ND + il], wdv1 = attn_w[ND + 16 + il];
        const int j0 = (gr0 & 1023) + mt * 32;

        #pragma unroll
        for (int g = 0; g < 2; ++g) {
            f32x4 cA = g ? c10 : c00;   // d = il
            f32x4 cB = g ? c11 : c01;   // d = 16+il
            const int jl = mt * 32 + g * 16 + ql * 4;   // local j in [0,64)

            // transpose into padded LDS — g stored as f16
            *(unsigned*)&trans[il][jl]          = pk_f16(cA[0], cA[1]);
            *(unsigned*)&trans[il][jl + 2]      = pk_f16(cA[2], cA[3]);
            *(unsigned*)&trans[16 + il][jl]     = pk_f16(cB[0], cB[1]);
            *(unsigned*)&trans[16 + il][jl + 2] = pk_f16(cB[2], cB[3]);

            const int jr = j0 + g * 16 + ql * 4;
            #pragma unroll
            for (int reg = 0; reg < 4; ++reg) {
                float ps = cA[reg] * wsv0 + cB[reg] * wsv1;
                float pd = cA[reg] * wdv0 + cB[reg] * wdv1;
                #pragma unroll
                for (int off = 1; off < 16; off <<= 1) {
                    ps += __shfl_xor(ps, off);
                    pd += __shfl_xor(pd, off);
                }
                if (il == 0) {
                    ssT[bh * NN + jr + reg] = ps;
                    sdT[bh * NN + jr + reg] = pd;
                }
            }
        }
    }
    __syncthreads();

    // coalesced gT store: thread t -> d = t>>3, 8 consecutive j (16 B)
    {
        const int d  = t >> 3;
        const int jo = (t & 7) * 8;
        uint4 v = *(const uint4*)&trans[d][jo];
        *(uint4*)(gT + ((size_t)(bh * ND) + d) * NN + (gr0 & 1023) + jo) = v;
    }
}

// ---------------------------------------------------------------------------
// Kernel 2 (exp-free MFMA attn, packed-f16 P path via inline-asm pk ops,
// pipelined loads, ones-MFMA denominator — R25 body verbatim):
// ---------------------------------------------------------------------------
__global__ __launch_bounds__(256, 4) void gat_attn_kernel(
    const unsigned short* __restrict__ gT, const float* __restrict__ ssT,
    const float* __restrict__ sdT, float* __restrict__ out)
{
    __shared__ __align__(16) unsigned short BpH[NN];   // 2 KB, f16 bits
    __shared__ __align__(16) unsigned short BnH[NN];   // 2 KB, f16 bits
    __shared__ f32x4 ccomb[2][12][64];                 // 24 KB
    __shared__ float red[4];

    const int bid = blockIdx.x;
    const int bh = bid & 63;                 // b*NH + h  (bid%8 = h)
    const int b = bh >> 3, h = bh & 7;
    const int i0 = (bid >> 6) * 64;
    const int t = threadIdx.x, lane = t & 63, jq = t >> 6;
    const int il = lane & 15, ql = lane >> 4;

    // ---- phase 0: BpH/BnH (f16) + global sd max + per-lane i-constants ----
    float sdv[4]; float M = -3.0e38f;
    #pragma unroll
    for (int q = 0; q < 4; ++q) {
        sdv[q] = sdT[bh * NN + t + 256 * q];
        M = fmaxf(M, sdv[q]);
    }
    #pragma unroll
    for (int off = 32; off >= 1; off >>= 1)
        M = fmaxf(M, __shfl_xor(M, off));
    if (lane == 0) red[jq] = M;
    #pragma unroll
    for (int q = 0; q < 4; ++q) {
        union { _Float16 h; unsigned short u; } cp, cn;
        cp.h = (_Float16)exp2f(sdv[q] * LOG2E);
        cn.h = (_Float16)exp2f(0.2f * LOG2E * sdv[q]);
        BpH[t + 256 * q] = cp.u;
        BnH[t + 256 * q] = cn.u;
    }
    __syncthreads();
    M = fmaxf(fmaxf(red[0], red[1]), fmaxf(red[2], red[3]));

    unsigned apw[4], anw[4];   // f16x2 splats as bit patterns
    #pragma unroll
    for (int mt = 0; mt < 4; ++mt) {
        const float si = ssT[bh * NN + i0 + mt * 16 + il];
        float x = si + M; x = fmaxf(x, 0.2f * x);
        const float mk = x * LOG2E;
        const float ah = exp2f(fmaf(si, LOG2E, -mk));
        const float nh = exp2f(fmaf(0.2f * si, LOG2E, -mk));
        apw[mt] = pk_f16(ah, ah);
        anw[mt] = pk_f16(nh, nh);
    }

    const unsigned short* gb0 = gT + ((size_t)(bh * ND) + il) * NN + jq * 256 + ql * 8;
    const unsigned short* gb1 = gb0 + 16 * NN;
    const unsigned short* bpq = BpH + jq * 256 + ql * 8;
    const unsigned short* bnq = BnH + jq * 256 + ql * 8;

    union { f16x8 v; unsigned u[4]; } ones;
    ones.u[0] = ones.u[1] = ones.u[2] = ones.u[3] = 0x3C003C00u;   // f16 1.0

    f32x4 c0[4], c1[4], cs[4];
    #pragma unroll
    for (int mt = 0; mt < 4; ++mt) {
        c0[mt] = (f32x4){0.f, 0.f, 0.f, 0.f};
        c1[mt] = c0[mt]; cs[mt] = c0[mt];
    }

    // ---- main loop: wave jq handles j in [jq*256, jq*256+256) ----
    // Software pipeline: gT (global) prefetch depth 4, Bp/Bn (LDS) depth 2.
    f16x8 b0b[4], b1b[4];
    union { uint4 q; unsigned w[4]; } pwb[2], nwb[2];
    #pragma unroll
    for (int s = 0; s < 4; ++s) {
        b0b[s] = *(const f16x8*)(gb0 + s * 32);
        b1b[s] = *(const f16x8*)(gb1 + s * 32);
    }
    #pragma unroll
    for (int s = 0; s < 2; ++s) {
        pwb[s].q = *(const uint4*)(bpq + s * 32);
        nwb[s].q = *(const uint4*)(bnq + s * 32);
    }

    #pragma unroll
    for (int s = 0; s < 8; ++s) {
        const int gbi = s & 3, lbi = s & 1;
        const f16x8 bf0 = b0b[gbi];
        const f16x8 bf1 = b1b[gbi];
        unsigned pw0 = pwb[lbi].w[0], pw1 = pwb[lbi].w[1];
        unsigned pw2 = pwb[lbi].w[2], pw3 = pwb[lbi].w[3];
        unsigned nw0 = nwb[lbi].w[0], nw1 = nwb[lbi].w[1];
        unsigned nw2 = nwb[lbi].w[2], nw3 = nwb[lbi].w[3];

        if (s < 4) {   // prefetch gT for s+4
            b0b[gbi] = *(const f16x8*)(gb0 + (s + 4) * 32);
            b1b[gbi] = *(const f16x8*)(gb1 + (s + 4) * 32);
        }
        if (s < 6) {   // prefetch Bp/Bn for s+2
            pwb[lbi].q = *(const uint4*)(bpq + (s + 2) * 32);
            nwb[lbi].q = *(const uint4*)(bnq + (s + 2) * 32);
        }

        const unsigned pww[4] = {pw0, pw1, pw2, pw3};
        const unsigned nww[4] = {nw0, nw1, nw2, nw3};
        #pragma unroll
        for (int mt = 0; mt < 4; ++mt) {
            union { f16x8 v; unsigned u[4]; } af;
            #pragma unroll
            for (int u = 0; u < 4; ++u)
                af.u[u] = pkmax(pkmul(pww[u], apw[mt]),
                                pkmul(nww[u], anw[mt]));
            c0[mt] = __builtin_amdgcn_mfma_f32_16x16x32_f16(af.v, bf0, c0[mt], 0, 0, 0);
            c1[mt] = __builtin_amdgcn_mfma_f32_16x16x32_f16(af.v, bf1, c1[mt], 0, 0, 0);
            cs[mt] = __builtin_amdgcn_mfma_f32_16x16x32_f16(af.v, ones.v, cs[mt], 0, 0, 0);
        }
    }

    // ---- quarter-combine tree: 2,3 -> 0,1; then 1 -> 0 ----
    if (jq >= 2) {
        #pragma unroll
        for (int mt = 0; mt < 4; ++mt) {
            ccomb[jq - 2][mt * 3 + 0][lane] = c0[mt];
            ccomb[jq - 2][mt * 3 + 1][lane] = c1[mt];
            ccomb[jq - 2][mt * 3 + 2][lane] = cs[mt];
        }
    }
    __syncthreads();
    if (jq < 2) {
        #pragma unroll
        for (int mt = 0; mt < 4; ++mt) {
            c0[mt] = c0[mt] + ccomb[jq][mt * 3 + 0][lane];
            c1[mt] = c1[mt] + ccomb[jq][mt * 3 + 1][lane];
            cs[mt] = cs[mt] + ccomb[jq][mt * 3 + 2][lane];
        }
    }
    __syncthreads();
    if (jq == 1) {
        #pragma unroll
        for (int mt = 0; mt < 4; ++mt) {
            ccomb[0][mt * 3 + 0][lane] = c0[mt];
            ccomb[0][mt * 3 + 1][lane] = c1[mt];
            ccomb[0][mt * 3 + 2][lane] = cs[mt];
        }
    }
    __syncthreads();
    if (jq == 0) {
        #pragma unroll
        for (int mt = 0; mt < 4; ++mt) {
            c0[mt] = c0[mt] + ccomb[0][mt * 3 + 0][lane];
            c1[mt] = c1[mt] + ccomb[0][mt * 3 + 1][lane];
            cs[mt] = cs[mt] + ccomb[0][mt * 3 + 2][lane];

            // C/D: col=il (d), row=ql*4+reg (i); cs[mt][reg] = S_i
            float* ob = out + (size_t)(b * NN + i0 + mt * 16 + ql * 4) * NOUT + h * ND + il;
            #pragma unroll
            for (int reg = 0; reg < 4; ++reg) {
                const float r = 1.0f / cs[mt][reg];
                ob[reg * NOUT]      = c0[mt][reg] * r;
                ob[reg * NOUT + 16] = c1[mt][reg] * r;
            }
        }
    }
}

// ---------------------------------------------------------------------------
extern "C" void kernel_launch(void* const* d_in, const int* in_sizes, int n_in,
                              void* d_out, int out_size, void* d_ws, size_t ws_size,
                              hipStream_t stream) {
    (void)in_sizes; (void)n_in; (void)out_size; (void)ws_size;
    const float* vertex = (const float*)d_in[0];
    const float* w_vert = (const float*)d_in[1];
    const float* attn_w = (const float*)d_in[2];
    float* out = (float*)d_out;

    char* ws = (char*)d_ws;
    unsigned short* gT = (unsigned short*)ws;                          // 4 MB
    float* ssT = (float*)(ws + ((size_t)NB * NH * ND * NN * 2));
    float* sdT = ssT + (size_t)NB * NH * NN;

    gat_gemm_kernel<<<dim3(128, NH), 256, 0, stream>>>(vertex, w_vert, attn_w,
                                                       gT, ssT, sdT);
    gat_attn_kernel<<<1024, 256, 0, stream>>>(gT, ssT, sdT, out);
}